// Round 9
// baseline (126.688 us; speedup 1.0000x reference)
//
#include <hip/hip_runtime.h>

#define H 256
#define NB 2048
#define BATCH 8
#define NSPLIT 8
#define KSPAN (NB / NSPLIT)   // 256 keys per split
#define NITER (KSPAN / 64)    // 4 double-buffered 64-key tiles

typedef unsigned short u16;
using bf16x8 = __attribute__((ext_vector_type(8))) __bf16;
using f32x4  = __attribute__((ext_vector_type(4))) float;

typedef const __attribute__((address_space(1))) void gv_t;
typedef __attribute__((address_space(3))) void lv_t;

// async 16B-per-lane global->LDS: lds dst is wave-uniform base, lane i lands at base+16*i
__device__ __forceinline__ void gl_lds16(const void* g, void* l) {
    __builtin_amdgcn_global_load_lds((gv_t*)g, (lv_t*)l, 16, 0, 0);
}

#define MFMA(a, b, c) __builtin_amdgcn_mfma_f32_16x16x32_bf16(a, b, c, 0, 0, 0)

__device__ __forceinline__ u16 f2bf(float f) {
    union { float f; unsigned u; } v; v.f = f;
    unsigned r = v.u + 0x7fffu + ((v.u >> 16) & 1u);  // RNE
    return (u16)(r >> 16);
}

__device__ __forceinline__ bf16x8 cvt8(const float* p) {
    float4 f0 = *(const float4*)p;
    float4 f1 = *(const float4*)(p + 4);
    union { bf16x8 v; u16 u[8]; } r;
    r.u[0] = f2bf(f0.x); r.u[1] = f2bf(f0.y); r.u[2] = f2bf(f0.z); r.u[3] = f2bf(f0.w);
    r.u[4] = f2bf(f1.x); r.u[5] = f2bf(f1.y); r.u[6] = f2bf(f1.z); r.u[7] = f2bf(f1.w);
    return r.v;
}

// ---- K1 prepA (merged wprep-reductions + aT-gemm + x-convert; all three paths
//   mutually independent -> one dispatch):
//   blocks 0..7:     aT[f][e] = bf16((Wk_bf[f,:]·Wq_bf[e,:])/16), weights
//                    converted f32->bf16 in-kernel (R2/R5-validated, absmax
//                    bit-identical) — kills the wqb/wkb roundtrip AND the
//                    wprep dispatch dependency.
//   blocks 8..263:   wvw[f] = Wv[f,:]·Ww, kbv[f] = Wk[f,:]·bq; f==0 adds cc = bv·Ww.
//                    (consumed by gemmTu next dispatch, not here)
//   blocks 264..4359: x -> bf16 only (uee moved to gemmTu). ----
__global__ __launch_bounds__(256) void prepA_kernel(
        const float* __restrict__ Wq, const float* __restrict__ Wk,
        const float* __restrict__ Wv, const float* __restrict__ Ww,
        const float* __restrict__ bq, const float* __restrict__ bv,
        const float* __restrict__ x,
        u16* __restrict__ aTb, float* __restrict__ wvw,
        float* __restrict__ kbv, float* __restrict__ ccp,
        u16* __restrict__ xbf) {
    __shared__ u16 bt[16384];   // 32KB fragment-major (gemm blocks only)
    int id = blockIdx.x, tid = threadIdx.x;

    if (id < 8) {   // ---- aT-gemm path (in-kernel weight conversion) ----
        int mb = (id >> 2) * 128, nb = (id & 3) * 64;
        int w = tid >> 6, lane = tid & 63;
        int l15 = lane & 15, quad = lane >> 4;

        {   // stage B = bf16(Wq rows nb..nb+63), fragment-major
            const float* src = Wq + (nb + w * 16 + l15) * H + quad * 8;
            #pragma unroll
            for (int ks = 0; ks < 8; ++ks)
                *(bf16x8*)(bt + (w * 8 + ks) * 512 + lane * 8) = cvt8(src + ks * 32);
        }

        bf16x8 a[2][8];
        #pragma unroll
        for (int mi = 0; mi < 2; ++mi) {
            const float* ab = Wk + (mb + w * 32 + mi * 16 + l15) * H + quad * 8;
            #pragma unroll
            for (int ks = 0; ks < 8; ++ks) a[mi][ks] = cvt8(ab + ks * 32);
        }
        __syncthreads();

        f32x4 acc[2][4] = {};
        #pragma unroll
        for (int ks = 0; ks < 8; ++ks)
            #pragma unroll
            for (int tt = 0; tt < 4; ++tt) {
                bf16x8 b = *(const bf16x8*)(bt + ((tt * 8 + ks) * 64 + lane) * 8);
                acc[0][tt] = MFMA(a[0][ks], b, acc[0][tt]);
                acc[1][tt] = MFMA(a[1][ks], b, acc[1][tt]);
            }

        #pragma unroll
        for (int mi = 0; mi < 2; ++mi) {
            int m = mb + w * 32 + mi * 16 + quad * 4;
            #pragma unroll
            for (int tt = 0; tt < 4; ++tt) {
                int n = nb + tt * 16 + l15;
                #pragma unroll
                for (int r2 = 0; r2 < 4; ++r2)
                    aTb[(size_t)(m + r2) * H + n] = f2bf(acc[mi][tt][r2] * 0.0625f);
            }
        }
        return;
    }

    if (id < 264) {   // ---- reduction path (was wprep, minus wqb/wkb) ----
        int f = id - 8, t = tid;
        float p = Wv[f * H + t] * Ww[t];
        float r = Wk[f * H + t] * bq[t];
        float c = (f == 0) ? bv[t] * Ww[t] : 0.f;
        for (int o = 32; o; o >>= 1) {
            p += __shfl_xor(p, o); r += __shfl_xor(r, o); c += __shfl_xor(c, o);
        }
        __shared__ float redp[4], redr[4], redc[4];
        int w = t >> 6, lane = t & 63;
        if (lane == 0) { redp[w] = p; redr[w] = r; redc[w] = c; }
        __syncthreads();
        if (t == 0) {
            wvw[f] = redp[0] + redp[1] + redp[2] + redp[3];
            kbv[f] = redr[0] + redr[1] + redr[2] + redr[3];
            if (f == 0) ccp[0] = redc[0] + redc[1] + redc[2] + redc[3];
        }
        return;
    }

    // ---- x -> bf16 convert path (uee moved to gemmTu) ----
    int lane = tid & 63;
    int row  = (id - 264) * 4 + (tid >> 6);
    float4 xv = *(const float4*)(x + (size_t)row * H + lane * 4);
    ushort4 o;
    o.x = f2bf(xv.x); o.y = f2bf(xv.y); o.z = f2bf(xv.z); o.w = f2bf(xv.w);
    *(ushort4*)(xbf + (size_t)row * H + lane * 4) = o;
}

// ---- K2 gemmTu: T = (xbf @ aT^T), bf16 MFMA (R8 gemm_bt specialized, scale=1)
//   + load-balanced uee slice: block (mb,nb) computes uee for rows
//   mb + nb*32 .. +31 (each row exactly once across the grid; 8 rows/wave,
//   cvtu's exact lane-parallel dot + o=32..1 shfl reduction — absmax proven
//   insensitive to this structure in R2/R5). uee work sits between the
//   gl_lds issue and __syncthreads so it hides under the staging drain.
//   u = x·wvw + cc, d = (x·kbv)/16, e = exp(d); uee[row] = {e*u, e}. ----
__global__ __launch_bounds__(256) void gemmTu_kernel(
        const u16* __restrict__ A, const u16* __restrict__ B,
        u16* __restrict__ C,
        const float* __restrict__ x, const float* __restrict__ wvw,
        const float* __restrict__ kbv, const float* __restrict__ ccp,
        float2* __restrict__ uee) {
    __shared__ u16 bt[16384];   // 32KB fragment-major
    int tid = threadIdx.x;
    int mb = blockIdx.x * 128, nbI = blockIdx.y, nb = nbI * 64;
    int w = tid >> 6, lane = tid & 63;
    int l15 = lane & 15, quad = lane >> 4;

    {   // wave w stages t=w, ks=0..7
        const u16* gsrc = B + (nb + w * 16 + l15) * H + quad * 8;
        for (int ks = 0; ks < 8; ++ks)
            gl_lds16(gsrc + ks * 32, bt + (w * 8 + ks) * 512);
    }

    bf16x8 a[2][8];
    for (int mi = 0; mi < 2; ++mi) {
        const u16* abase = A + (size_t)(mb + w * 32 + mi * 16 + l15) * H + quad * 8;
        for (int ks = 0; ks < 8; ++ks) a[mi][ks] = *(const bf16x8*)(abase + ks * 32);
    }

    {   // ---- uee slice: 32 rows for this block, 8 per wave ----
        int rbase = mb + nbI * 32 + w * 8;
        float cc = ccp[0];
        float4 wv = *(const float4*)(wvw + lane * 4);
        float4 kv = *(const float4*)(kbv + lane * 4);
        #pragma unroll
        for (int rr = 0; rr < 8; ++rr) {
            int row = rbase + rr;
            float4 xv = *(const float4*)(x + (size_t)row * H + lane * 4);
            float s = xv.x * wv.x + xv.y * wv.y + xv.z * wv.z + xv.w * wv.w;
            float d = xv.x * kv.x + xv.y * kv.y + xv.z * kv.z + xv.w * kv.w;
            for (int o2 = 32; o2; o2 >>= 1) {
                s += __shfl_xor(s, o2); d += __shfl_xor(d, o2);
            }
            if (lane == 0) {
                float e = __expf(d * 0.0625f);
                uee[row] = make_float2(e * (s + cc), e);
            }
        }
    }
    __syncthreads();

    f32x4 acc[2][4] = {};
    for (int ks = 0; ks < 8; ++ks)
        for (int t = 0; t < 4; ++t) {
            bf16x8 b = *(const bf16x8*)(bt + ((t * 8 + ks) * 64 + lane) * 8);
            acc[0][t] = MFMA(a[0][ks], b, acc[0][t]);
            acc[1][t] = MFMA(a[1][ks], b, acc[1][t]);
        }

    for (int mi = 0; mi < 2; ++mi) {
        int m = mb + w * 32 + mi * 16 + quad * 4;
        for (int t = 0; t < 4; ++t) {
            int n = nb + t * 16 + l15;
            for (int r = 0; r < 4; ++r)
                C[(size_t)(m + r) * H + n] = f2bf(acc[mi][t][r]);
        }
    }
}

// ---- attention (R8/R1 best-measured kernel, verbatim): logit(n,m) = T[n]·x[m];
//      num += e^logit·(e·u)_m, den += e^logit·e_m.  64-key double-buffered
//      tiles, t-outer/ks-inner, M=4 (64 q-rows/wave), one barrier per tile.
//      Grid 512 = 2 blocks/CU; b in low 3 bits pins batch b -> XCD b. ----
__global__ __launch_bounds__(256, 2) void attn_kernel(
        const u16* __restrict__ T, const u16* __restrict__ xbf,
        const float2* __restrict__ uee,
        float* __restrict__ pnum, float* __restrict__ pden) {
    __shared__ u16 kt[32768];   // 2 x 32KB fragment-major 64-key tiles
    int tid = threadIdx.x;
    int id = blockIdx.x;
    int b = id & 7, rest = id >> 3;
    int qc = rest & 7, sp = rest >> 3;
    int w = tid >> 6, lane = tid & 63, l15 = lane & 15, quad = lane >> 4;
    int qb = qc * 256;

    // resident A fragments: 64 q-rows per wave (4 x 16)
    bf16x8 aq[4][8];
    {
        const u16* qbase = T + (size_t)(b * NB + qb + w * 64 + l15) * H + quad * 8;
        #pragma unroll
        for (int mi = 0; mi < 4; ++mi)
            #pragma unroll
            for (int ks = 0; ks < 8; ++ks)
                aq[mi][ks] = *(const bf16x8*)(qbase + mi * 16 * H + ks * 32);
    }

    const u16* xb = xbf + (size_t)b * NB * H;
    const float2* uep = uee + (size_t)b * NB;
    const int kb0 = sp * KSPAN;

    // wave w stages t-group w (16 keys, 8 ks-chunks of 1KB) of each 64-key tile
    const u16* gsrc = xb + (size_t)(kb0 + w * 16 + l15) * H + quad * 8;
    #pragma unroll
    for (int j = 0; j < 8; ++j)
        gl_lds16(gsrc + j * 32, kt + (w * 8 + j) * 512);
    __syncthreads();

    float ls[4][4] = {}, as_[4][4] = {};

    #pragma unroll 1
    for (int h = 0; h < NITER; ++h) {
        const u16* ktc = kt + (h & 1) * 16384;
        if (h + 1 < NITER) {   // stage next 64-key tile into the other buffer
            u16* dst = kt + ((h & 1) ^ 1) * 16384;
            const u16* g2 = gsrc + (size_t)(h + 1) * 64 * H;
            #pragma unroll
            for (int j = 0; j < 8; ++j)
                gl_lds16(g2 + j * 32, dst + (w * 8 + j) * 512);
        }
        int kb64 = kb0 + h * 64;
        float2 uv[4];
        #pragma unroll
        for (int t = 0; t < 4; ++t) uv[t] = uep[kb64 + t * 16 + l15];

        #pragma unroll
        for (int t = 0; t < 4; ++t) {
            f32x4 acc[4] = {};
            #pragma unroll
            for (int ks = 0; ks < 8; ++ks) {
                bf16x8 bfr = *(const bf16x8*)(ktc + ((t * 8 + ks) * 64 + lane) * 8);
                acc[0] = MFMA(aq[0][ks], bfr, acc[0]);
                acc[1] = MFMA(aq[1][ks], bfr, acc[1]);
                acc[2] = MFMA(aq[2][ks], bfr, acc[2]);
                acc[3] = MFMA(aq[3][ks], bfr, acc[3]);
            }
            #pragma unroll
            for (int mi = 0; mi < 4; ++mi)
                #pragma unroll
                for (int r = 0; r < 4; ++r) {
                    float p = __expf(acc[mi][r]);
                    as_[mi][r] += p * uv[t].x;
                    ls[mi][r]  += p * uv[t].y;
                }
        }
        __syncthreads();
    }

    // reduce over the 16 key-columns (l15)
    #pragma unroll
    for (int mi = 0; mi < 4; ++mi)
        #pragma unroll
        for (int r = 0; r < 4; ++r)
            for (int o = 1; o < 16; o <<= 1) {
                ls[mi][r]  += __shfl_xor(ls[mi][r], o);
                as_[mi][r] += __shfl_xor(as_[mi][r], o);
            }

    if (l15 == 0) {
        size_t base = (size_t)(sp * BATCH + b) * NB + qb + w * 64 + quad * 4;
        #pragma unroll
        for (int mi = 0; mi < 4; ++mi)
            #pragma unroll
            for (int r = 0; r < 4; ++r) {
                pnum[base + mi * 16 + r] = as_[mi][r];
                pden[base + mi * 16 + r] = ls[mi][r];
            }
    }
}

// ---- combine K-splits: out = sum(num)/sum(den) + bw ----
__global__ __launch_bounds__(256) void finalize_kernel(
        const float* __restrict__ pnum, const float* __restrict__ pden,
        const float* __restrict__ bw, float* __restrict__ out) {
    int i = blockIdx.x * 256 + threadIdx.x;   // i = b*NB + n
    float num = 0.f, den = 0.f;
    for (int sp = 0; sp < NSPLIT; ++sp) {
        num += pnum[sp * (BATCH * NB) + i];
        den += pden[sp * (BATCH * NB) + i];
    }
    out[i] = num / den + bw[0];
}

extern "C" void kernel_launch(void* const* d_in, const int* in_sizes, int n_in,
                              void* d_out, int out_size, void* d_ws, size_t ws_size,
                              hipStream_t stream) {
    (void)in_sizes; (void)n_in; (void)out_size; (void)ws_size;
    const float* x  = (const float*)d_in[0];
    const float* Wq = (const float*)d_in[1];
    const float* bq = (const float*)d_in[2];
    const float* Wk = (const float*)d_in[3];
    const float* bk = (const float*)d_in[4];  (void)bk;  // cancels in softmax
    const float* Wv = (const float*)d_in[5];
    const float* bv = (const float*)d_in[6];
    const float* Ww = (const float*)d_in[7];
    const float* bw = (const float*)d_in[8];
    float* out = (float*)d_out;

    u16* xbf = (u16*)d_ws;                     // 4194304 u16 (8 MB)
    u16* Tbf = xbf + 4194304;                  // 4194304 u16 (8 MB)
    u16* aTb = Tbf + 4194304;                  // 65536 u16
    float* wvw = (float*)(aTb + 65536);        // 256 f32
    float* kbv = wvw + 256;                    // 256 f32
    float* ccp = kbv + 256;                    // 4 f32 (1 used, keeps 8B align)
    float2* uee = (float2*)(ccp + 4);          // 16384 float2
    float* pnum = (float*)(uee + 16384);       // NSPLIT*16384 f32
    float* pden = pnum + NSPLIT * BATCH * NB;  // NSPLIT*16384 f32

    // merged: blocks 0..7 aT-gemm, 8..263 reductions, 264..4359 x->bf16
    hipLaunchKernelGGL(prepA_kernel, dim3(4360), dim3(256), 0, stream,
                       Wq, Wk, Wv, Ww, bq, bv, x, aTb, wvw, kbv, ccp, xbf);
    // T = xbf @ aT^T, + uee (needs wvw/kbv/cc from prepA)
    hipLaunchKernelGGL(gemmTu_kernel, dim3(128, 4), dim3(256), 0, stream,
                       xbf, aTb, Tbf, x, wvw, kbv, ccp, uee);
    hipLaunchKernelGGL(attn_kernel, dim3(8 * 8 * NSPLIT), dim3(256), 0, stream,
                       Tbf, xbf, uee, pnum, pden);
    hipLaunchKernelGGL(finalize_kernel, dim3(64), dim3(256), 0, stream,
                       pnum, pden, bw, out);
}

// Round 10
// 123.969 us; speedup vs baseline: 1.0219x; 1.0219x over previous
//
#include <hip/hip_runtime.h>

#define H 256
#define NB 2048
#define BATCH 8
#define NSPLIT 8
#define KSPAN (NB / NSPLIT)   // 256 keys per split
#define NITER (KSPAN / 64)    // 4 double-buffered 64-key tiles

typedef unsigned short u16;
using bf16x8 = __attribute__((ext_vector_type(8))) __bf16;
using f32x4  = __attribute__((ext_vector_type(4))) float;

typedef const __attribute__((address_space(1))) void gv_t;
typedef __attribute__((address_space(3))) void lv_t;

// async 16B-per-lane global->LDS: lds dst is wave-uniform base, lane i lands at base+16*i
__device__ __forceinline__ void gl_lds16(const void* g, void* l) {
    __builtin_amdgcn_global_load_lds((gv_t*)g, (lv_t*)l, 16, 0, 0);
}

#define MFMA(a, b, c) __builtin_amdgcn_mfma_f32_16x16x32_bf16(a, b, c, 0, 0, 0)

__device__ __forceinline__ u16 f2bf(float f) {
    union { float f; unsigned u; } v; v.f = f;
    unsigned r = v.u + 0x7fffu + ((v.u >> 16) & 1u);  // RNE
    return (u16)(r >> 16);
}

__device__ __forceinline__ bf16x8 cvt8(const float* p) {
    float4 f0 = *(const float4*)p;
    float4 f1 = *(const float4*)(p + 4);
    union { bf16x8 v; u16 u[8]; } r;
    r.u[0] = f2bf(f0.x); r.u[1] = f2bf(f0.y); r.u[2] = f2bf(f0.z); r.u[3] = f2bf(f0.w);
    r.u[4] = f2bf(f1.x); r.u[5] = f2bf(f1.y); r.u[6] = f2bf(f1.z); r.u[7] = f2bf(f1.w);
    return r.v;
}

// ---- K1 prepA (R9 verbatim — validated component, absmax bit-identical):
//   blocks 0..7:     aT[f][e] = bf16((Wk_bf[f,:]·Wq_bf[e,:])/16), weights
//                    converted f32->bf16 in-kernel.
//   blocks 8..263:   wvw[f] = Wv[f,:]·Ww, kbv[f] = Wk[f,:]·bq; f==0 adds cc = bv·Ww.
//   blocks 264..4359: x -> bf16. ----
__global__ __launch_bounds__(256) void prepA_kernel(
        const float* __restrict__ Wq, const float* __restrict__ Wk,
        const float* __restrict__ Wv, const float* __restrict__ Ww,
        const float* __restrict__ bq, const float* __restrict__ bv,
        const float* __restrict__ x,
        u16* __restrict__ aTb, float* __restrict__ wvw,
        float* __restrict__ kbv, float* __restrict__ ccp,
        u16* __restrict__ xbf) {
    __shared__ u16 bt[16384];   // 32KB fragment-major (gemm blocks only)
    int id = blockIdx.x, tid = threadIdx.x;

    if (id < 8) {   // ---- aT-gemm path (in-kernel weight conversion) ----
        int mb = (id >> 2) * 128, nb = (id & 3) * 64;
        int w = tid >> 6, lane = tid & 63;
        int l15 = lane & 15, quad = lane >> 4;

        {   // stage B = bf16(Wq rows nb..nb+63), fragment-major
            const float* src = Wq + (nb + w * 16 + l15) * H + quad * 8;
            #pragma unroll
            for (int ks = 0; ks < 8; ++ks)
                *(bf16x8*)(bt + (w * 8 + ks) * 512 + lane * 8) = cvt8(src + ks * 32);
        }

        bf16x8 a[2][8];
        #pragma unroll
        for (int mi = 0; mi < 2; ++mi) {
            const float* ab = Wk + (mb + w * 32 + mi * 16 + l15) * H + quad * 8;
            #pragma unroll
            for (int ks = 0; ks < 8; ++ks) a[mi][ks] = cvt8(ab + ks * 32);
        }
        __syncthreads();

        f32x4 acc[2][4] = {};
        #pragma unroll
        for (int ks = 0; ks < 8; ++ks)
            #pragma unroll
            for (int tt = 0; tt < 4; ++tt) {
                bf16x8 b = *(const bf16x8*)(bt + ((tt * 8 + ks) * 64 + lane) * 8);
                acc[0][tt] = MFMA(a[0][ks], b, acc[0][tt]);
                acc[1][tt] = MFMA(a[1][ks], b, acc[1][tt]);
            }

        #pragma unroll
        for (int mi = 0; mi < 2; ++mi) {
            int m = mb + w * 32 + mi * 16 + quad * 4;
            #pragma unroll
            for (int tt = 0; tt < 4; ++tt) {
                int n = nb + tt * 16 + l15;
                #pragma unroll
                for (int r2 = 0; r2 < 4; ++r2)
                    aTb[(size_t)(m + r2) * H + n] = f2bf(acc[mi][tt][r2] * 0.0625f);
            }
        }
        return;
    }

    if (id < 264) {   // ---- reduction path ----
        int f = id - 8, t = tid;
        float p = Wv[f * H + t] * Ww[t];
        float r = Wk[f * H + t] * bq[t];
        float c = (f == 0) ? bv[t] * Ww[t] : 0.f;
        for (int o = 32; o; o >>= 1) {
            p += __shfl_xor(p, o); r += __shfl_xor(r, o); c += __shfl_xor(c, o);
        }
        __shared__ float redp[4], redr[4], redc[4];
        int w = t >> 6, lane = t & 63;
        if (lane == 0) { redp[w] = p; redr[w] = r; redc[w] = c; }
        __syncthreads();
        if (t == 0) {
            wvw[f] = redp[0] + redp[1] + redp[2] + redp[3];
            kbv[f] = redr[0] + redr[1] + redr[2] + redr[3];
            if (f == 0) ccp[0] = redc[0] + redc[1] + redc[2] + redc[3];
        }
        return;
    }

    // ---- x -> bf16 convert path ----
    int lane = tid & 63;
    int row  = (id - 264) * 4 + (tid >> 6);
    float4 xv = *(const float4*)(x + (size_t)row * H + lane * 4);
    ushort4 o;
    o.x = f2bf(xv.x); o.y = f2bf(xv.y); o.z = f2bf(xv.z); o.w = f2bf(xv.w);
    *(ushort4*)(xbf + (size_t)row * H + lane * 4) = o;
}

// ---- K2 gemmTu2 (block-split, prepA pattern — uee on DEDICATED blocks, not
//   inline in the gemm critical path (R9's +8.3 µs lesson)):
//   blocks 0..511:    T = (xbf @ aT^T), R8 gemm_bt verbatim (flattened grid).
//   blocks 512..4607: uee — cvtu's exact 1-wave-per-row dot+shfl structure
//                     (bit-identical numerics), cc from ccp (R9-validated).
//                     16 MB x-read backfills idle CUs under the gemm. ----
__global__ __launch_bounds__(256) void gemmTu2_kernel(
        const u16* __restrict__ A, const u16* __restrict__ B,
        u16* __restrict__ C,
        const float* __restrict__ x, const float* __restrict__ wvw,
        const float* __restrict__ kbv, const float* __restrict__ ccp,
        float2* __restrict__ uee) {
    __shared__ u16 bt[16384];   // 32KB fragment-major (gemm blocks only)
    int id = blockIdx.x, tid = threadIdx.x;

    if (id < 512) {   // ---- gemmT path (R8 verbatim; grid flattened 128x4) ----
        int mb = (id & 127) * 128, nb = (id >> 7) * 64;
        int w = tid >> 6, lane = tid & 63;
        int l15 = lane & 15, quad = lane >> 4;

        {   // wave w stages t=w, ks=0..7
            const u16* gsrc = B + (nb + w * 16 + l15) * H + quad * 8;
            for (int ks = 0; ks < 8; ++ks)
                gl_lds16(gsrc + ks * 32, bt + (w * 8 + ks) * 512);
        }

        bf16x8 a[2][8];
        for (int mi = 0; mi < 2; ++mi) {
            const u16* abase = A + (size_t)(mb + w * 32 + mi * 16 + l15) * H + quad * 8;
            for (int ks = 0; ks < 8; ++ks) a[mi][ks] = *(const bf16x8*)(abase + ks * 32);
        }
        __syncthreads();

        f32x4 acc[2][4] = {};
        for (int ks = 0; ks < 8; ++ks)
            for (int t = 0; t < 4; ++t) {
                bf16x8 b = *(const bf16x8*)(bt + ((t * 8 + ks) * 64 + lane) * 8);
                acc[0][t] = MFMA(a[0][ks], b, acc[0][t]);
                acc[1][t] = MFMA(a[1][ks], b, acc[1][t]);
            }

        for (int mi = 0; mi < 2; ++mi) {
            int m = mb + w * 32 + mi * 16 + quad * 4;
            for (int t = 0; t < 4; ++t) {
                int n = nb + t * 16 + l15;
                for (int r = 0; r < 4; ++r)
                    C[(size_t)(m + r) * H + n] = f2bf(acc[mi][t][r]);
            }
        }
        return;
    }

    // ---- uee path (cvtu structure: one wave per row, 4 rows/block) ----
    int lane = tid & 63;
    int row  = (id - 512) * 4 + (tid >> 6);
    float4 xv = *(const float4*)(x + (size_t)row * H + lane * 4);
    float4 wv = *(const float4*)(wvw + lane * 4);
    float s = xv.x * wv.x + xv.y * wv.y + xv.z * wv.z + xv.w * wv.w;
    float4 kv = *(const float4*)(kbv + lane * 4);
    float d = xv.x * kv.x + xv.y * kv.y + xv.z * kv.z + xv.w * kv.w;
    for (int o2 = 32; o2; o2 >>= 1) {
        s += __shfl_xor(s, o2); d += __shfl_xor(d, o2);
    }
    if (lane == 0) {
        float e = __expf(d * 0.0625f);
        uee[row] = make_float2(e * (s + ccp[0]), e);
    }
}

// ---- attention (R8/R1 best-measured kernel, verbatim): logit(n,m) = T[n]·x[m];
//      num += e^logit·(e·u)_m, den += e^logit·e_m.  64-key double-buffered
//      tiles, t-outer/ks-inner, M=4 (64 q-rows/wave), one barrier per tile.
//      Grid 512 = 2 blocks/CU; b in low 3 bits pins batch b -> XCD b. ----
__global__ __launch_bounds__(256, 2) void attn_kernel(
        const u16* __restrict__ T, const u16* __restrict__ xbf,
        const float2* __restrict__ uee,
        float* __restrict__ pnum, float* __restrict__ pden) {
    __shared__ u16 kt[32768];   // 2 x 32KB fragment-major 64-key tiles
    int tid = threadIdx.x;
    int id = blockIdx.x;
    int b = id & 7, rest = id >> 3;
    int qc = rest & 7, sp = rest >> 3;
    int w = tid >> 6, lane = tid & 63, l15 = lane & 15, quad = lane >> 4;
    int qb = qc * 256;

    // resident A fragments: 64 q-rows per wave (4 x 16)
    bf16x8 aq[4][8];
    {
        const u16* qbase = T + (size_t)(b * NB + qb + w * 64 + l15) * H + quad * 8;
        #pragma unroll
        for (int mi = 0; mi < 4; ++mi)
            #pragma unroll
            for (int ks = 0; ks < 8; ++ks)
                aq[mi][ks] = *(const bf16x8*)(qbase + mi * 16 * H + ks * 32);
    }

    const u16* xb = xbf + (size_t)b * NB * H;
    const float2* uep = uee + (size_t)b * NB;
    const int kb0 = sp * KSPAN;

    // wave w stages t-group w (16 keys, 8 ks-chunks of 1KB) of each 64-key tile
    const u16* gsrc = xb + (size_t)(kb0 + w * 16 + l15) * H + quad * 8;
    #pragma unroll
    for (int j = 0; j < 8; ++j)
        gl_lds16(gsrc + j * 32, kt + (w * 8 + j) * 512);
    __syncthreads();

    float ls[4][4] = {}, as_[4][4] = {};

    #pragma unroll 1
    for (int h = 0; h < NITER; ++h) {
        const u16* ktc = kt + (h & 1) * 16384;
        if (h + 1 < NITER) {   // stage next 64-key tile into the other buffer
            u16* dst = kt + ((h & 1) ^ 1) * 16384;
            const u16* g2 = gsrc + (size_t)(h + 1) * 64 * H;
            #pragma unroll
            for (int j = 0; j < 8; ++j)
                gl_lds16(g2 + j * 32, dst + (w * 8 + j) * 512);
        }
        int kb64 = kb0 + h * 64;
        float2 uv[4];
        #pragma unroll
        for (int t = 0; t < 4; ++t) uv[t] = uep[kb64 + t * 16 + l15];

        #pragma unroll
        for (int t = 0; t < 4; ++t) {
            f32x4 acc[4] = {};
            #pragma unroll
            for (int ks = 0; ks < 8; ++ks) {
                bf16x8 bfr = *(const bf16x8*)(ktc + ((t * 8 + ks) * 64 + lane) * 8);
                acc[0] = MFMA(aq[0][ks], bfr, acc[0]);
                acc[1] = MFMA(aq[1][ks], bfr, acc[1]);
                acc[2] = MFMA(aq[2][ks], bfr, acc[2]);
                acc[3] = MFMA(aq[3][ks], bfr, acc[3]);
            }
            #pragma unroll
            for (int mi = 0; mi < 4; ++mi)
                #pragma unroll
                for (int r = 0; r < 4; ++r) {
                    float p = __expf(acc[mi][r]);
                    as_[mi][r] += p * uv[t].x;
                    ls[mi][r]  += p * uv[t].y;
                }
        }
        __syncthreads();
    }

    // reduce over the 16 key-columns (l15)
    #pragma unroll
    for (int mi = 0; mi < 4; ++mi)
        #pragma unroll
        for (int r = 0; r < 4; ++r)
            for (int o = 1; o < 16; o <<= 1) {
                ls[mi][r]  += __shfl_xor(ls[mi][r], o);
                as_[mi][r] += __shfl_xor(as_[mi][r], o);
            }

    if (l15 == 0) {
        size_t base = (size_t)(sp * BATCH + b) * NB + qb + w * 64 + quad * 4;
        #pragma unroll
        for (int mi = 0; mi < 4; ++mi)
            #pragma unroll
            for (int r = 0; r < 4; ++r) {
                pnum[base + mi * 16 + r] = as_[mi][r];
                pden[base + mi * 16 + r] = ls[mi][r];
            }
    }
}

// ---- combine K-splits: out = sum(num)/sum(den) + bw ----
__global__ __launch_bounds__(256) void finalize_kernel(
        const float* __restrict__ pnum, const float* __restrict__ pden,
        const float* __restrict__ bw, float* __restrict__ out) {
    int i = blockIdx.x * 256 + threadIdx.x;   // i = b*NB + n
    float num = 0.f, den = 0.f;
    for (int sp = 0; sp < NSPLIT; ++sp) {
        num += pnum[sp * (BATCH * NB) + i];
        den += pden[sp * (BATCH * NB) + i];
    }
    out[i] = num / den + bw[0];
}

extern "C" void kernel_launch(void* const* d_in, const int* in_sizes, int n_in,
                              void* d_out, int out_size, void* d_ws, size_t ws_size,
                              hipStream_t stream) {
    (void)in_sizes; (void)n_in; (void)out_size; (void)ws_size;
    const float* x  = (const float*)d_in[0];
    const float* Wq = (const float*)d_in[1];
    const float* bq = (const float*)d_in[2];
    const float* Wk = (const float*)d_in[3];
    const float* bk = (const float*)d_in[4];  (void)bk;  // cancels in softmax
    const float* Wv = (const float*)d_in[5];
    const float* bv = (const float*)d_in[6];
    const float* Ww = (const float*)d_in[7];
    const float* bw = (const float*)d_in[8];
    float* out = (float*)d_out;

    u16* xbf = (u16*)d_ws;                     // 4194304 u16 (8 MB)
    u16* Tbf = xbf + 4194304;                  // 4194304 u16 (8 MB)
    u16* aTb = Tbf + 4194304;                  // 65536 u16
    float* wvw = (float*)(aTb + 65536);        // 256 f32
    float* kbv = wvw + 256;                    // 256 f32
    float* ccp = kbv + 256;                    // 4 f32 (1 used, keeps 8B align)
    float2* uee = (float2*)(ccp + 4);          // 16384 float2
    float* pnum = (float*)(uee + 16384);       // NSPLIT*16384 f32
    float* pden = pnum + NSPLIT * BATCH * NB;  // NSPLIT*16384 f32

    // merged: blocks 0..7 aT-gemm, 8..263 reductions, 264..4359 x->bf16
    hipLaunchKernelGGL(prepA_kernel, dim3(4360), dim3(256), 0, stream,
                       Wq, Wk, Wv, Ww, bq, bv, x, aTb, wvw, kbv, ccp, xbf);
    // merged: blocks 0..511 T = xbf @ aT^T, 512..4607 uee
    hipLaunchKernelGGL(gemmTu2_kernel, dim3(4608), dim3(256), 0, stream,
                       xbf, aTb, Tbf, x, wvw, kbv, ccp, uee);
    hipLaunchKernelGGL(attn_kernel, dim3(8 * 8 * NSPLIT), dim3(256), 0, stream,
                       Tbf, xbf, uee, pnum, pden);
    hipLaunchKernelGGL(finalize_kernel, dim3(64), dim3(256), 0, stream,
                       pnum, pden, bw, out);
}

// Round 11
// 123.208 us; speedup vs baseline: 1.0282x; 1.0062x over previous
//
#include <hip/hip_runtime.h>

#define H 256
#define NB 2048
#define BATCH 8
#define NSPLIT 8
#define KSPAN (NB / NSPLIT)   // 256 keys per split
#define NITER (KSPAN / 64)    // 4 double-buffered 64-key tiles

typedef unsigned short u16;
using bf16x8 = __attribute__((ext_vector_type(8))) __bf16;
using f32x4  = __attribute__((ext_vector_type(4))) float;

typedef const __attribute__((address_space(1))) void gv_t;
typedef __attribute__((address_space(3))) void lv_t;

// async 16B-per-lane global->LDS: lds dst is wave-uniform base, lane i lands at base+16*i
__device__ __forceinline__ void gl_lds16(const void* g, void* l) {
    __builtin_amdgcn_global_load_lds((gv_t*)g, (lv_t*)l, 16, 0, 0);
}

#define MFMA(a, b, c) __builtin_amdgcn_mfma_f32_16x16x32_bf16(a, b, c, 0, 0, 0)

__device__ __forceinline__ u16 f2bf(float f) {
    union { float f; unsigned u; } v; v.f = f;
    unsigned r = v.u + 0x7fffu + ((v.u >> 16) & 1u);  // RNE
    return (u16)(r >> 16);
}

// ---- coalesced weight prep (one block per row f):
//   wqb/wkb = bf16(Wq/Wk) row-major; wvw[f] = Wv[f,:]·Ww; kbv[f] = Wk[f,:]·bq ----
__global__ __launch_bounds__(256) void wprep_kernel(
        const float* __restrict__ Wq, const float* __restrict__ Wk,
        const float* __restrict__ Wv, const float* __restrict__ Ww,
        const float* __restrict__ bq,
        u16* __restrict__ wqb, u16* __restrict__ wkb,
        float* __restrict__ wvw, float* __restrict__ kbv) {
    int f = blockIdx.x, t = threadIdx.x;
    float wq = Wq[f * H + t];
    wqb[f * H + t] = f2bf(wq);
    float wk = Wk[f * H + t];
    wkb[f * H + t] = f2bf(wk);
    float p = Wv[f * H + t] * Ww[t];
    float r = wk * bq[t];
    for (int o = 32; o; o >>= 1) { p += __shfl_xor(p, o); r += __shfl_xor(r, o); }
    __shared__ float redp[4], redr[4];
    int w = t >> 6, lane = t & 63;
    if (lane == 0) { redp[w] = p; redr[w] = r; }
    __syncthreads();
    if (t == 0) {
        wvw[f] = redp[0] + redp[1] + redp[2] + redp[3];
        kbv[f] = redr[0] + redr[1] + redr[2] + redr[3];
    }
}

// ---- K2 merged (block-split; both paths byte-identical to the R1 kernels):
//   blocks 0..7:    aT[f][e] = (wkb[f,:]·wqb[e,:])/16  (bf16 MFMA gemm)
//   blocks 8..4103: cvtu — x -> bf16; per-row u = x·wvw + bv·Ww, d = (x·kbv)/16,
//                   e = exp(d); uee[row] = {e*u, e}.  One wave per row.
//   aT-gemm blocks come FIRST so aTb is ready early; gemmT waits on both anyway. ----
__global__ __launch_bounds__(256) void prep2_kernel(
        const u16* __restrict__ wkb, const u16* __restrict__ wqb,
        u16* __restrict__ aTb,
        const float* __restrict__ x, const float* __restrict__ wvw,
        const float* __restrict__ kbv, const float* __restrict__ bv,
        const float* __restrict__ Ww,
        u16* __restrict__ xbf, float2* __restrict__ uee) {
    __shared__ u16 bt[16384];   // 32KB fragment-major (gemm blocks only)
    int id = blockIdx.x, tid = threadIdx.x;

    if (id < 8) {   // ---- aT-gemm path (R1 gemm_bt, A=wkb, B=wqb, scale=1/16) ----
        int mb = (id >> 2) * 128, nb = (id & 3) * 64;
        int w = tid >> 6, lane = tid & 63;
        int l15 = lane & 15, quad = lane >> 4;

        {   // wave w stages t=w, ks=0..7
            const u16* gsrc = wqb + (nb + w * 16 + l15) * H + quad * 8;
            for (int ks = 0; ks < 8; ++ks)
                gl_lds16(gsrc + ks * 32, bt + (w * 8 + ks) * 512);
        }

        bf16x8 a[2][8];
        for (int mi = 0; mi < 2; ++mi) {
            const u16* abase = wkb + (size_t)(mb + w * 32 + mi * 16 + l15) * H + quad * 8;
            for (int ks = 0; ks < 8; ++ks) a[mi][ks] = *(const bf16x8*)(abase + ks * 32);
        }
        __syncthreads();

        f32x4 acc[2][4] = {};
        for (int ks = 0; ks < 8; ++ks)
            for (int t = 0; t < 4; ++t) {
                bf16x8 b = *(const bf16x8*)(bt + ((t * 8 + ks) * 64 + lane) * 8);
                acc[0][t] = MFMA(a[0][ks], b, acc[0][t]);
                acc[1][t] = MFMA(a[1][ks], b, acc[1][t]);
            }

        for (int mi = 0; mi < 2; ++mi) {
            int m = mb + w * 32 + mi * 16 + quad * 4;
            for (int t = 0; t < 4; ++t) {
                int n = nb + t * 16 + l15;
                for (int r = 0; r < 4; ++r)
                    aTb[(size_t)(m + r) * H + n] = f2bf(acc[mi][t][r] * 0.0625f);
            }
        }
        return;
    }

    // ---- cvtu path (R1 cvtu, verbatim; row base shifted by the 8 gemm blocks) ----
    int lane = tid & 63;
    int row  = (id - 8) * 4 + (tid >> 6);
    float4 xv = *(const float4*)(x + row * H + lane * 4);
    ushort4 o;
    o.x = f2bf(xv.x); o.y = f2bf(xv.y); o.z = f2bf(xv.z); o.w = f2bf(xv.w);
    *(ushort4*)(xbf + row * H + lane * 4) = o;
    float4 wv = *(const float4*)(wvw + lane * 4);
    float s = xv.x * wv.x + xv.y * wv.y + xv.z * wv.z + xv.w * wv.w;
    float4 kv = *(const float4*)(kbv + lane * 4);
    float d = xv.x * kv.x + xv.y * kv.y + xv.z * kv.z + xv.w * kv.w;
    float4 bvv = *(const float4*)(bv + lane * 4);
    float4 www = *(const float4*)(Ww + lane * 4);
    float c = bvv.x * www.x + bvv.y * www.y + bvv.z * www.z + bvv.w * www.w;
    for (int o2 = 32; o2; o2 >>= 1) {
        s += __shfl_xor(s, o2); d += __shfl_xor(d, o2); c += __shfl_xor(c, o2);
    }
    if (lane == 0) {
        float e = __expf(d * 0.0625f);
        uee[row] = make_float2(e * (s + c), e);
    }
}

// ---- generic C = (A @ B^T) * scale, bf16 in/out, MFMA 16x16x32, M=2/wave. ----
__global__ __launch_bounds__(256) void gemm_bt_kernel(
        const u16* __restrict__ A, const u16* __restrict__ B,
        u16* __restrict__ C, float scale) {
    __shared__ u16 bt[16384];   // 32KB fragment-major
    int tid = threadIdx.x;
    int mb = blockIdx.x * 128, nb = blockIdx.y * 64;
    int w = tid >> 6, lane = tid & 63;
    int l15 = lane & 15, quad = lane >> 4;

    {   // wave w stages t=w, ks=0..7
        const u16* gsrc = B + (nb + w * 16 + l15) * H + quad * 8;
        for (int ks = 0; ks < 8; ++ks)
            gl_lds16(gsrc + ks * 32, bt + (w * 8 + ks) * 512);
    }

    bf16x8 a[2][8];
    for (int mi = 0; mi < 2; ++mi) {
        const u16* abase = A + (size_t)(mb + w * 32 + mi * 16 + l15) * H + quad * 8;
        for (int ks = 0; ks < 8; ++ks) a[mi][ks] = *(const bf16x8*)(abase + ks * 32);
    }
    __syncthreads();

    f32x4 acc[2][4] = {};
    for (int ks = 0; ks < 8; ++ks)
        for (int t = 0; t < 4; ++t) {
            bf16x8 b = *(const bf16x8*)(bt + ((t * 8 + ks) * 64 + lane) * 8);
            acc[0][t] = MFMA(a[0][ks], b, acc[0][t]);
            acc[1][t] = MFMA(a[1][ks], b, acc[1][t]);
        }

    for (int mi = 0; mi < 2; ++mi) {
        int m = mb + w * 32 + mi * 16 + quad * 4;
        for (int t = 0; t < 4; ++t) {
            int n = nb + t * 16 + l15;
            for (int r = 0; r < 4; ++r)
                C[(size_t)(m + r) * H + n] = f2bf(acc[mi][t][r] * scale);
        }
    }
}

// ---- attention (best-measured kernel, verbatim): logit(n,m) = T[n]·x[m];
//      num += e^logit·(e·u)_m, den += e^logit·e_m.  64-key double-buffered
//      tiles, t-outer/ks-inner, M=4 (64 q-rows/wave), one barrier per tile.
//      Grid 512 = 2 blocks/CU; b in low 3 bits pins batch b -> XCD b. ----
__global__ __launch_bounds__(256, 2) void attn_kernel(
        const u16* __restrict__ T, const u16* __restrict__ xbf,
        const float2* __restrict__ uee,
        float* __restrict__ pnum, float* __restrict__ pden) {
    __shared__ u16 kt[32768];   // 2 x 32KB fragment-major 64-key tiles
    int tid = threadIdx.x;
    int id = blockIdx.x;
    int b = id & 7, rest = id >> 3;
    int qc = rest & 7, sp = rest >> 3;
    int w = tid >> 6, lane = tid & 63, l15 = lane & 15, quad = lane >> 4;
    int qb = qc * 256;

    // resident A fragments: 64 q-rows per wave (4 x 16)
    bf16x8 aq[4][8];
    {
        const u16* qbase = T + (size_t)(b * NB + qb + w * 64 + l15) * H + quad * 8;
        #pragma unroll
        for (int mi = 0; mi < 4; ++mi)
            #pragma unroll
            for (int ks = 0; ks < 8; ++ks)
                aq[mi][ks] = *(const bf16x8*)(qbase + mi * 16 * H + ks * 32);
    }

    const u16* xb = xbf + (size_t)b * NB * H;
    const float2* uep = uee + (size_t)b * NB;
    const int kb0 = sp * KSPAN;

    // wave w stages t-group w (16 keys, 8 ks-chunks of 1KB) of each 64-key tile
    const u16* gsrc = xb + (size_t)(kb0 + w * 16 + l15) * H + quad * 8;
    #pragma unroll
    for (int j = 0; j < 8; ++j)
        gl_lds16(gsrc + j * 32, kt + (w * 8 + j) * 512);
    __syncthreads();

    float ls[4][4] = {}, as_[4][4] = {};

    #pragma unroll 1
    for (int h = 0; h < NITER; ++h) {
        const u16* ktc = kt + (h & 1) * 16384;
        if (h + 1 < NITER) {   // stage next 64-key tile into the other buffer
            u16* dst = kt + ((h & 1) ^ 1) * 16384;
            const u16* g2 = gsrc + (size_t)(h + 1) * 64 * H;
            #pragma unroll
            for (int j = 0; j < 8; ++j)
                gl_lds16(g2 + j * 32, dst + (w * 8 + j) * 512);
        }
        int kb64 = kb0 + h * 64;
        float2 uv[4];
        #pragma unroll
        for (int t = 0; t < 4; ++t) uv[t] = uep[kb64 + t * 16 + l15];

        #pragma unroll
        for (int t = 0; t < 4; ++t) {
            f32x4 acc[4] = {};
            #pragma unroll
            for (int ks = 0; ks < 8; ++ks) {
                bf16x8 bfr = *(const bf16x8*)(ktc + ((t * 8 + ks) * 64 + lane) * 8);
                acc[0] = MFMA(aq[0][ks], bfr, acc[0]);
                acc[1] = MFMA(aq[1][ks], bfr, acc[1]);
                acc[2] = MFMA(aq[2][ks], bfr, acc[2]);
                acc[3] = MFMA(aq[3][ks], bfr, acc[3]);
            }
            #pragma unroll
            for (int mi = 0; mi < 4; ++mi)
                #pragma unroll
                for (int r = 0; r < 4; ++r) {
                    float p = __expf(acc[mi][r]);
                    as_[mi][r] += p * uv[t].x;
                    ls[mi][r]  += p * uv[t].y;
                }
        }
        __syncthreads();
    }

    // reduce over the 16 key-columns (l15)
    #pragma unroll
    for (int mi = 0; mi < 4; ++mi)
        #pragma unroll
        for (int r = 0; r < 4; ++r)
            for (int o = 1; o < 16; o <<= 1) {
                ls[mi][r]  += __shfl_xor(ls[mi][r], o);
                as_[mi][r] += __shfl_xor(as_[mi][r], o);
            }

    if (l15 == 0) {
        size_t base = (size_t)(sp * BATCH + b) * NB + qb + w * 64 + quad * 4;
        #pragma unroll
        for (int mi = 0; mi < 4; ++mi)
            #pragma unroll
            for (int r = 0; r < 4; ++r) {
                pnum[base + mi * 16 + r] = as_[mi][r];
                pden[base + mi * 16 + r] = ls[mi][r];
            }
    }
}

// ---- combine K-splits: out = sum(num)/sum(den) + bw ----
__global__ __launch_bounds__(256) void finalize_kernel(
        const float* __restrict__ pnum, const float* __restrict__ pden,
        const float* __restrict__ bw, float* __restrict__ out) {
    int i = blockIdx.x * 256 + threadIdx.x;   // i = b*NB + n
    float num = 0.f, den = 0.f;
    for (int sp = 0; sp < NSPLIT; ++sp) {
        num += pnum[sp * (BATCH * NB) + i];
        den += pden[sp * (BATCH * NB) + i];
    }
    out[i] = num / den + bw[0];
}

extern "C" void kernel_launch(void* const* d_in, const int* in_sizes, int n_in,
                              void* d_out, int out_size, void* d_ws, size_t ws_size,
                              hipStream_t stream) {
    (void)in_sizes; (void)n_in; (void)out_size; (void)ws_size;
    const float* x  = (const float*)d_in[0];
    const float* Wq = (const float*)d_in[1];
    const float* bq = (const float*)d_in[2];
    const float* Wk = (const float*)d_in[3];
    const float* bk = (const float*)d_in[4];  (void)bk;  // cancels in softmax
    const float* Wv = (const float*)d_in[5];
    const float* bv = (const float*)d_in[6];
    const float* Ww = (const float*)d_in[7];
    const float* bw = (const float*)d_in[8];
    float* out = (float*)d_out;

    u16* xbf = (u16*)d_ws;                     // 4194304 u16 (8 MB)
    u16* Tbf = xbf + 4194304;                  // 4194304 u16 (8 MB)
    u16* aTb = Tbf + 4194304;                  // 65536 u16
    u16* wqb = aTb + 65536;                    // 65536 u16
    u16* wkb = wqb + 65536;                    // 65536 u16
    float* wvw = (float*)(wkb + 65536);        // 256 f32
    float* kbv = wvw + 256;                    // 256 f32
    float2* uee = (float2*)(kbv + 256);        // 16384 float2
    float* pnum = (float*)(uee + 16384);       // NSPLIT*16384 f32
    float* pden = pnum + NSPLIT * BATCH * NB;  // NSPLIT*16384 f32

    hipLaunchKernelGGL(wprep_kernel, dim3(256), dim3(256), 0, stream,
                       Wq, Wk, Wv, Ww, bq, wqb, wkb, wvw, kbv);
    // merged: blocks 0..7 aT-gemm, blocks 8..4103 cvtu
    hipLaunchKernelGGL(prep2_kernel, dim3(4104), dim3(256), 0, stream,
                       wkb, wqb, aTb, x, wvw, kbv, bv, Ww, xbf, uee);
    // T = xbf @ aT^T (aTb rows are B-operand rows)
    hipLaunchKernelGGL(gemm_bt_kernel, dim3(128, 4), dim3(256), 0, stream,
                       xbf, aTb, Tbf, 1.0f);
    hipLaunchKernelGGL(attn_kernel, dim3(8 * 8 * NSPLIT), dim3(256), 0, stream,
                       Tbf, xbf, uee, pnum, pden);
    hipLaunchKernelGGL(finalize_kernel, dim3(64), dim3(256), 0, stream,
                       pnum, pden, bw, out);
}